// Round 3
// baseline (494.564 us; speedup 1.0000x reference)
//
#include <hip/hip_runtime.h>

// FeaturesEmbedding: out[b, f-1, :] = sum_{n: x_field[b,n]==f} table[x[b,n] + f*100000, :] * x_val[b,n]
// B=8192, NNZ=64, NUM_FIELDS=16 (field 0 skipped), EMBED=64, FIELD_DIM=100000.

#define BATCH      8192
#define NNZ        64
#define EMBED      64
#define FIELD_DIM  100000
#define NOUT_F     15   // fields 1..15

// One wave (64 lanes) per batch row. Lane t owns embedding dim t.
// 8192 blocks x 1 wave = 8192 waves = 256 CU x 32 wave slots -> full occupancy
// for latency hiding on the random 256B row gathers.
__global__ __launch_bounds__(64) void femb_kernel(
    const int*   __restrict__ x_field,
    const int*   __restrict__ x,
    const float* __restrict__ x_val,
    const float* __restrict__ table,
    float*       __restrict__ out)
{
    const int b = blockIdx.x;
    const int t = threadIdx.x;            // 0..63 == embedding dim

    // Per-lane runtime-indexable accumulators. Lane t only touches column t:
    // no cross-lane sharing, no __syncthreads needed (single wave).
    // Addresses stride 4B across lanes -> 2 lanes/bank aliasing (free on CDNA4).
    __shared__ float acc[NOUT_F * EMBED];
#pragma unroll
    for (int j = 0; j < NOUT_F; ++j) acc[j * EMBED + t] = 0.0f;

    // Coalesced metadata load: lane t holds item t's (field, idx, weight).
    const int   base     = b * NNZ;
    const int   my_field = x_field[base + t];
    const int   my_x     = x[base + t];
    const float my_w     = x_val[base + t];

    // Iterate items; broadcast item i's metadata to all lanes via shfl.
    // Gather is a fully coalesced 256B row read (lane t reads float t of the row).
    // f is wave-uniform -> the skip branch does not diverge.
#pragma unroll 8
    for (int i = 0; i < NNZ; ++i) {
        const int   f  = __shfl(my_field, i);
        const int   xi = __shfl(my_x, i);
        const float w  = __shfl(my_w, i);
        if (f != 0) {
            const size_t row = (size_t)(xi + f * FIELD_DIM);
            const float  v   = table[row * EMBED + t];
            acc[(f - 1) * EMBED + t] += v * w;
        }
    }

    // Coalesced output: 15 rows of 64 floats.
    float* o = out + (size_t)b * (NOUT_F * EMBED);
#pragma unroll
    for (int j = 0; j < NOUT_F; ++j) o[j * EMBED + t] = acc[j * EMBED + t];
}

extern "C" void kernel_launch(void* const* d_in, const int* in_sizes, int n_in,
                              void* d_out, int out_size, void* d_ws, size_t ws_size,
                              hipStream_t stream) {
    const int*   x_field = (const int*)d_in[0];
    const int*   x       = (const int*)d_in[1];
    const float* x_val   = (const float*)d_in[2];
    const float* table   = (const float*)d_in[3];
    float*       out     = (float*)d_out;

    femb_kernel<<<BATCH, 64, 0, stream>>>(x_field, x, x_val, table, out);
}